// Round 5
// baseline (244.019 us; speedup 1.0000x reference)
//
#include <hip/hip_runtime.h>
#include <cstdint>
#include <cstddef>

#define NA 8400   // anchors per image: 80*80 + 40*40 + 20*20
#define NAP 8448  // padded stride (33*256)
#define NB 32     // batch
#define NG 20     // ground truths per image
#define NCL 80    // classes
#define NBLK 33   // 256-thread blocks per image

// ---------- fast math ----------
__device__ __forceinline__ float frcp(float x) { return __builtin_amdgcn_rcpf(x); }
__device__ __forceinline__ float bce0(float x) {
  return fmaxf(x, 0.0f) + __logf(1.0f + __expf(-fabsf(x)));
}

__device__ __forceinline__ void anchor_info(int a, const float* p8, const float* p16,
                                            const float* p32, int b, const float*& base,
                                            int& hw, int& HW, int& xg, int& yg, float& fs) {
  if (a < 6400)      { hw = a;        HW = 6400; xg = hw % 80; yg = hw / 80; fs = 8.f;
                       base = p8  + (size_t)b * 85 * 6400; }
  else if (a < 8000) { hw = a - 6400; HW = 1600; xg = hw % 40; yg = hw / 40; fs = 16.f;
                       base = p16 + (size_t)b * 85 * 1600; }
  else               { hw = a - 8000; HW = 400;  xg = hw % 20; yg = hw / 20; fs = 32.f;
                       base = p32 + (size_t)b * 85 * 400; }
}

__device__ __forceinline__ float iou_raw(float gx, float gy, float gw, float gh, float4 p) {
  float gtlx = gx - gw * 0.5f, gtly = gy - gh * 0.5f;
  float gbrx = gx + gw * 0.5f, gbry = gy + gh * 0.5f;
  float ptlx = p.x - p.z * 0.5f, ptly = p.y - p.w * 0.5f;
  float pbrx = p.x + p.z * 0.5f, pbry = p.y + p.w * 0.5f;
  float tlx = fmaxf(gtlx, ptlx), tly = fmaxf(gtly, ptly);
  float brx = fminf(gbrx, pbrx), bry = fminf(gbry, pbry);
  float inter = ((tlx < brx) && (tly < bry)) ? (brx - tlx) * (bry - tly) : 0.0f;
  float ag = gw * gh, ap = p.z * p.w;
  return inter * frcp(ag + ap - inter + 1e-16f);
}

__device__ __forceinline__ float giou_loss(float4 bb, float gx, float gy, float gw, float gh) {
  float btlx = bb.x - bb.z * 0.5f, btly = bb.y - bb.w * 0.5f;
  float bbrx = bb.x + bb.z * 0.5f, bbry = bb.y + bb.w * 0.5f;
  float gtlx = gx - gw * 0.5f, gtly = gy - gh * 0.5f;
  float gbrx = gx + gw * 0.5f, gbry = gy + gh * 0.5f;
  float tlx = fmaxf(btlx, gtlx), tly = fmaxf(btly, gtly);
  float brx = fminf(bbrx, gbrx), bry = fminf(bbry, gbry);
  float area_b = bb.z * bb.w, area_g = gw * gh;
  float inter = ((tlx < brx) && (tly < bry)) ? (brx - tlx) * (bry - tly) : 0.0f;
  float uni = area_b + area_g - inter;
  float iou = inter / (uni + 1e-16f);
  float ctlx = fminf(btlx, gtlx), ctly = fminf(btly, gtly);
  float cbrx = fmaxf(bbrx, gbrx), cbry = fmaxf(bbry, gbry);
  float area_c = fmaxf((cbrx - ctlx) * (cbry - ctly), 1e-16f);
  float giou = iou - (area_c - uni) / area_c;
  giou = fminf(fmaxf(giou, -1.0f), 1.0f);
  return 1.0f - giou;
}

// ---------- kA: fused geometry/compaction/decode + class sums + cost/iou table ----------
// Phase 1 (k1): per-anchor fg test, block compaction (one atomicAdd), obj-BCE partial,
// fg data kept in LDS. Phase 2 (k23): per block-local fg anchor, 8 thr/anchor class
// sums then cost/iou rows — all block-local, zero cross-block sync.
__global__ __launch_bounds__(256) void kA(const float* __restrict__ p8,
                                          const float* __restrict__ p16,
                                          const float* __restrict__ p32,
                                          const float* __restrict__ labels,
                                          int* __restrict__ n_fg_cnt,
                                          int* __restrict__ fg_list,
                                          float4* __restrict__ bbox_c,
                                          float* __restrict__ sb_c,
                                          float2* __restrict__ ct_tbl,
                                          float* __restrict__ blk_obj) {
  __shared__ float s_gt[NG * 4];
  __shared__ int   s_gcls[NG];
  __shared__ int   s_a[256];
  __shared__ unsigned int s_m[256];
  __shared__ float s_lso[256];
  __shared__ float4 s_bb[256];
  __shared__ float s_sl[8][33];
  __shared__ float s_sbv[8][33];
  __shared__ float s_slr[32];
  __shared__ unsigned int s_wcnt[4];
  __shared__ float s_part[4];
  __shared__ unsigned int s_base;
  __shared__ int s_cnt;

  int blk = blockIdx.x, b = blockIdx.y, tid = threadIdx.x, lane = tid & 63, wid = tid >> 6;
  size_t bo = (size_t)b * NAP;

  if (tid < NG) {
    s_gt[tid * 4 + 0] = labels[((size_t)b * NG + tid) * 5 + 0];
    s_gt[tid * 4 + 1] = labels[((size_t)b * NG + tid) * 5 + 1];
    s_gt[tid * 4 + 2] = labels[((size_t)b * NG + tid) * 5 + 2];
    s_gt[tid * 4 + 3] = labels[((size_t)b * NG + tid) * 5 + 3];
    s_gcls[tid] = (int)labels[((size_t)b * NG + tid) * 5 + 4];
  }
  __syncthreads();

  // ---- phase 1: fg test + decode ----
  int a = blk * 256 + tid;
  bool fg = false;
  unsigned int msk = 0u;
  float bce_obj = 0.0f, obj = 0.0f;
  const float* base = nullptr; int hw = 0, HW = 0, xg = 0, yg = 0; float fs = 8.f;
  if (a < NA) {
    anchor_info(a, p8, p16, p32, b, base, hw, HW, xg, yg, fs);
    obj = base[4 * HW + hw];             // coalesced obj-plane stream
    bce_obj = bce0(obj);
    float xc = ((float)xg + 0.5f) * fs;
    float yc = ((float)yg + 0.5f) * fs;
    float r = 2.5f * fs;
#pragma unroll
    for (int g = 0; g < NG; ++g) {
      float gx = s_gt[g * 4 + 0], gy = s_gt[g * 4 + 1];
      float gw = s_gt[g * 4 + 2], gh = s_gt[g * 4 + 3];
      bool inb = (xc > gx - 0.5f * gw) && (xc < gx + 0.5f * gw) &&
                 (yc > gy - 0.5f * gh) && (yc < gy + 0.5f * gh);
      bool inc = (xc > gx - r) && (xc < gx + r) && (yc > gy - r) && (yc < gy + r);
      fg = fg || inb || inc;
      if (inb && inc) msk |= (1u << g);
    }
  }

  unsigned long long bm = __ballot(fg);
#pragma unroll
  for (int off = 32; off; off >>= 1) bce_obj += __shfl_down(bce_obj, off, 64);
  if (lane == 0) { s_wcnt[wid] = (unsigned int)__popcll(bm); s_part[wid] = bce_obj; }
  __syncthreads();
  if (tid == 0) {
    unsigned int cnt = s_wcnt[0] + s_wcnt[1] + s_wcnt[2] + s_wcnt[3];
    s_cnt = (int)cnt;
    s_base = cnt ? (unsigned int)atomicAdd(&n_fg_cnt[b], (int)cnt) : 0u;
    blk_obj[b * NBLK + blk] = s_part[0] + s_part[1] + s_part[2] + s_part[3];
  }
  __syncthreads();

  if (fg) {
    unsigned int li = 0;
    for (int w = 0; w < wid; ++w) li += s_wcnt[w];
    li += (unsigned int)__popcll(bm & ((1ull << lane) - 1ull));
    float v0 = base[hw];
    float v1 = base[HW + hw];
    float v2 = base[2 * HW + hw];
    float v3 = base[3 * HW + hw];
    float4 bb4 = make_float4((v0 + (float)xg) * fs, (v1 + (float)yg) * fs,
                             __expf(v2) * fs, __expf(v3) * fs);
    float uo = __logf(1.0f + __expf(-fabsf(obj)));
    float lso = fminf(obj, 0.0f) - uo;
    s_a[li] = a; s_m[li] = msk; s_lso[li] = lso; s_bb[li] = bb4;
    int ci = (int)(s_base + li);
    fg_list[bo + ci] = a;
    bbox_c[bo + ci] = bb4;
  }
  __syncthreads();

  // ---- phase 2: class sums + cost/iou rows over the block's own fg anchors ----
  int cnt = s_cnt;
  int part = tid >> 5, cl = tid & 31;
  for (int t0 = 0; t0 < cnt; t0 += 32) {
    int idx = t0 + cl;
    bool act = idx < cnt;
    const float* base2 = nullptr; int hw2 = 0, HW2 = 0, xg2, yg2; float fs2;
    float lso = 0.0f, sl = 0.0f, sb = 0.0f;
    if (act) {
      int a2 = s_a[idx];
      lso = s_lso[idx];
      anchor_info(a2, p8, p16, p32, b, base2, hw2, HW2, xg2, yg2, fs2);
      const float* cb = base2 + (size_t)(5 + part * 10) * HW2 + hw2;
      float xs[10];
#pragma unroll
      for (int j = 0; j < 10; ++j) xs[j] = cb[(size_t)j * HW2];
#pragma unroll
      for (int j = 0; j < 10; ++j) {
        float x = xs[j];
        float u = __logf(1.0f + __expf(-fabsf(x)));
        sb += fmaxf(x, 0.0f) + u;                 // bce(x,0)
        float lsx = fminf(x, 0.0f) - u;           // log(sigmoid(x))
        float lpr = 0.5f * (lsx + lso);           // log p
        float p   = __expf(lpr);
        sl += fmaxf(__logf(1.0f - p), -100.0f);
      }
    }
    s_sl[part][cl] = sl;
    s_sbv[part][cl] = sb;
    __syncthreads();
    if (tid < 32) {
      float tsl = 0.0f, tsb = 0.0f;
#pragma unroll
      for (int q = 0; q < 8; ++q) { tsl += s_sl[q][tid]; tsb += s_sbv[q][tid]; }
      s_slr[tid] = tsl;
      if (t0 + tid < cnt) sb_c[bo + s_base + t0 + tid] = tsb;
    }
    __syncthreads();
    if (act) {
      float slr = s_slr[cl];
      unsigned int am = s_m[idx];
      float4 pb = s_bb[idx];
      int ci = (int)(s_base) + idx;
#pragma unroll
      for (int gg = 0; gg < 3; ++gg) {
        int g = part + (gg << 3);
        if (g < NG) {
          int cg = s_gcls[g];
          float x = base2[(size_t)(5 + cg) * HW2 + hw2];
          float u = __logf(1.0f + __expf(-fabsf(x)));
          float lsx = fminf(x, 0.0f) - u;
          float lpr = 0.5f * (lsx + lso);
          float p   = __expf(lpr);
          float l1p = fmaxf(__logf(1.0f - p), -100.0f);
          float wv  = fmaxf(lpr, -100.0f) - l1p;  // lp - l1p
          float iou = iou_raw(s_gt[g * 4 + 0], s_gt[g * 4 + 1],
                              s_gt[g * 4 + 2], s_gt[g * 4 + 3], pb);
          float cst = -(wv + slr) - 3.0f * __logf(iou + 1e-8f);
          if (!((am >> g) & 1u)) cst += 100000.0f;
          ct_tbl[((size_t)b * NG + g) * NAP + ci] = make_float2(cst, iou);
        }
      }
    }
    __syncthreads();   // protect s_sl/s_sbv/s_slr reuse next tile
  }
}

// ---------- kE: one block per image — row top-k scans + LDS marks + finalize ----------
// 640 threads = 10 waves; wave w owns rows g = 2w, 2w+1 (full-row scan per wave).
// Marks go to an LDS mask; one __syncthreads; block-local finalize; last-image
// ticket emits the scalar. No cross-block phase chain.
__global__ __launch_bounds__(640) void kE(const float* __restrict__ p8,
                                          const float* __restrict__ p16,
                                          const float* __restrict__ p32,
                                          const float* __restrict__ labels,
                                          const float2* __restrict__ ct_tbl,
                                          const int* __restrict__ n_fg,
                                          const int* __restrict__ fg_list,
                                          const float4* __restrict__ bbox_c,
                                          const float* __restrict__ sb_c,
                                          const float* __restrict__ blk_obj,
                                          float* __restrict__ accum,
                                          int* __restrict__ done,
                                          float* __restrict__ out) {
  __shared__ unsigned int s_mask[NAP];   // 33 KB
  __shared__ float s_gt[NG * 5];
  __shared__ float s_red[40];
  __shared__ int s_flag;

  int b = blockIdx.x, tid = threadIdx.x;
  int lane = tid & 63, wid = tid >> 6;
  int n = n_fg[b];
  size_t bo = (size_t)b * NAP;

  for (int i = tid; i < NAP; i += 640) s_mask[i] = 0u;
  if (tid < NG * 5) s_gt[tid] = labels[(size_t)b * NG * 5 + tid];
  __syncthreads();

  // ---- per-wave row scans: 2 rows per wave ----
#pragma unroll
  for (int gi = 0; gi < 2; ++gi) {
    int g = wid * 2 + gi;
    const float2* __restrict__ row = ct_tbl + ((size_t)b * NG + g) * NAP;
    float t10[10];
    float c10v[10];
    int   c10i[10];
#pragma unroll
    for (int j = 0; j < 10; ++j) { t10[j] = 0.0f; c10v[j] = 3.4e38f; c10i[j] = 0x7fffffff; }

    for (int ci = lane; ci < n; ci += 64) {
      float2 e = row[ci];
      float cst = e.x, iou = e.y;
      if (iou > t10[9]) {
        t10[9] = iou;
#pragma unroll
        for (int q = 9; q > 0; --q) {
          if (t10[q] > t10[q - 1]) { float t = t10[q]; t10[q] = t10[q - 1]; t10[q - 1] = t; }
          else break;
        }
      }
      if (cst < c10v[9] || (cst == c10v[9] && ci < c10i[9])) {
        c10v[9] = cst; c10i[9] = ci;
#pragma unroll
        for (int q = 9; q > 0; --q) {
          if (c10v[q] < c10v[q - 1] ||
              (c10v[q] == c10v[q - 1] && c10i[q] < c10i[q - 1])) {
            float tv = c10v[q]; c10v[q] = c10v[q - 1]; c10v[q - 1] = tv;
            int   ti = c10i[q]; c10i[q] = c10i[q - 1]; c10i[q - 1] = ti;
          } else break;
        }
      }
    }

    // dyn_k: 10 wave-max rounds over iou (descending sum order = reference)
    float s = 0.0f;
    for (int r = 0; r < 10; ++r) {
      float v = t10[0];
      float bv = v;
#pragma unroll
      for (int off = 32; off; off >>= 1) bv = fmaxf(bv, __shfl_down(bv, off, 64));
      bv = __shfl(bv, 0, 64);
      s += bv;
      unsigned long long won = __ballot(v == bv);
      if (lane == __ffsll(won) - 1) {
#pragma unroll
        for (int q = 0; q < 9; ++q) t10[q] = t10[q + 1];
        t10[9] = -1.0f;
      }
    }
    int k = (int)s;
    if (k < 1) k = 1;

    // mark k smallest (cost,ci) via wave-min rounds
    for (int it = 0; it < k; ++it) {
      float cv = c10v[0]; int cix = c10i[0];
      float cbv = cv;     int cbi = cix;
#pragma unroll
      for (int off = 32; off; off >>= 1) {
        float ov = __shfl_down(cbv, off, 64);
        int   oi = __shfl_down(cbi, off, 64);
        if (ov < cbv || (ov == cbv && oi < cbi)) { cbv = ov; cbi = oi; }
      }
      cbv = __shfl(cbv, 0, 64);
      cbi = __shfl(cbi, 0, 64);
      if (cbv >= 1e37f) break;           // exhausted real candidates
      if (cv == cbv && cix == cbi) {     // unique owner
        atomicOr(&s_mask[cbi], 1u << g);
#pragma unroll
        for (int q = 0; q < 9; ++q) { c10v[q] = c10v[q + 1]; c10i[q] = c10i[q + 1]; }
        c10v[9] = 3.4e38f; c10i[9] = 0x7fffffff;
      }
    }
  }
  __syncthreads();

  // ---- block-local finalize ----
  float li = 0.0f, oe = 0.0f, lc = 0.0f, nf = 0.0f;
  for (int ci = tid; ci < n; ci += 640) {
    unsigned int m = s_mask[ci];
    if (m == 0u) continue;
    int mg;
    if (m & (m - 1)) {
      float bestc = 3.4e38f; mg = 0;
#pragma unroll 4
      for (int gq = 0; gq < NG; ++gq) {
        float cst = ct_tbl[((size_t)b * NG + gq) * NAP + ci].x;
        if (cst < bestc) { bestc = cst; mg = gq; }
      }
    } else {
      mg = __ffs(m) - 1;
    }
    int a = fg_list[bo + ci];
    const float* base; int hw, HW, xg, yg; float fs;
    anchor_info(a, p8, p16, p32, b, base, hw, HW, xg, yg, fs);
    float4 pb = bbox_c[bo + ci];
    float gx = s_gt[mg * 5], gy = s_gt[mg * 5 + 1];
    float gw = s_gt[mg * 5 + 2], gh = s_gt[mg * 5 + 3];
    int cgq = (int)s_gt[mg * 5 + 4];
    float piou = ct_tbl[((size_t)b * NG + mg) * NAP + ci].y;
    li += giou_loss(pb, gx, gy, gw, gh);
    float xcls = base[(size_t)(5 + cgq) * HW + hw];
    lc += sb_c[bo + ci] - xcls * piou;   // bce(x,t) = bce(x,0) - x*t
    oe += base[4 * HW + hw];             // obj logit: bce(x,1) = bce(x,0) - x
    nf += 1.0f;
  }

  float vals[4] = {li, oe, lc, nf};
#pragma unroll
  for (int q2 = 0; q2 < 4; ++q2) {
#pragma unroll
    for (int off = 32; off; off >>= 1) vals[q2] += __shfl_down(vals[q2], off, 64);
  }
  if (lane == 0) {
    s_red[wid * 4 + 0] = vals[0];
    s_red[wid * 4 + 1] = vals[1];
    s_red[wid * 4 + 2] = vals[2];
    s_red[wid * 4 + 3] = vals[3];
  }
  __syncthreads();
  if (tid < 4) {
    const int slot[4] = {0, 2, 3, 4};
    float s = 0.0f;
#pragma unroll
    for (int w = 0; w < 10; ++w) s += s_red[w * 4 + tid];
    if (s != 0.0f) atomicAdd(&accum[slot[tid]], s);
  }
  __syncthreads();

  // ---- final ticket: last image's block emits the scalar ----
  if (tid == 0) {
    __threadfence();
    s_flag = (atomicAdd(done, 1) == NB - 1) ? 1 : 0;
  }
  __syncthreads();
  if (!s_flag) return;

  float s = 0.0f;
  for (int i = tid; i < NB * NBLK; i += 640) s += blk_obj[i];  // obj-BCE base
#pragma unroll
  for (int off = 32; off; off >>= 1) s += __shfl_down(s, off, 64);
  if (lane == 0) s_red[wid] = s;
  __syncthreads();
  if (tid == 0) {
    float obj_base = 0.0f;
#pragma unroll
    for (int w = 0; w < 10; ++w) obj_base += s_red[w];
    float loss_iou = atomicAdd(&accum[0], 0.0f);   // coherent read-backs
    float oex      = atomicAdd(&accum[2], 0.0f);
    float loss_cls = atomicAdd(&accum[3], 0.0f);
    float num_fg   = atomicAdd(&accum[4], 0.0f);
    float loss_obj = obj_base - oex;
    out[0] = (5.0f * loss_iou + loss_obj + loss_cls) / fmaxf(num_fg, 1.0f);
  }
}

// ---------- launch ----------
extern "C" void kernel_launch(void* const* d_in, const int* in_sizes, int n_in,
                              void* d_out, int out_size, void* d_ws, size_t ws_size,
                              hipStream_t stream) {
  const float* p8     = (const float*)d_in[0];
  const float* p16    = (const float*)d_in[1];
  const float* p32    = (const float*)d_in[2];
  const float* labels = (const float*)d_in[3];
  float* out = (float*)d_out;

  const size_t BAP = (size_t)NB * NAP;     // 270336
  char* w = (char*)d_ws;
  float4*       bbox_c   = (float4*)w;                             // 4.33 MB, 16B-aligned
  float2*       ct_tbl   = (float2*)(w + BAP * 16);                // NB*NG*NAP*8 = 43.2 MB
  char*         w2       = (char*)ct_tbl + (size_t)NB * NG * NAP * 8;
  int*          fg_list  = (int*)(w2);
  float*        sb_c     = (float*)(w2 + BAP * 4);
  char*         w3       = w2 + BAP * 8;
  // zeroed region (512 B): n_fg(32i)@0, accum(8f)@128, done@384
  int*          n_fg     = (int*)w3;
  float*        accum    = (float*)(w3 + 128);
  int*          done     = (int*)(w3 + 384);
  float*        blk_obj  = (float*)(w3 + 512);                     // NB*NBLK floats (4224 B)

  hipMemsetAsync(w3, 0, 512, stream);

  kA<<<dim3(NBLK, NB), dim3(256), 0, stream>>>(p8, p16, p32, labels, n_fg, fg_list,
                                               bbox_c, sb_c, ct_tbl, blk_obj);
  kE<<<dim3(NB), dim3(640), 0, stream>>>(p8, p16, p32, labels, ct_tbl, n_fg, fg_list,
                                         bbox_c, sb_c, blk_obj, accum, done, out);
}

// Round 6
// 188.262 us; speedup vs baseline: 1.2962x; 1.2962x over previous
//
#include <hip/hip_runtime.h>
#include <cstdint>
#include <cstddef>

#define NA 8400   // anchors per image: 80*80 + 40*40 + 20*20
#define NAP 8448  // padded stride (33*256)
#define NB 32     // batch
#define NG 20     // ground truths per image
#define NCL 80    // classes
#define NBLK 33   // 256-thread blocks per image

// ---------- fast math ----------
__device__ __forceinline__ float frcp(float x) { return __builtin_amdgcn_rcpf(x); }
__device__ __forceinline__ float bce0(float x) {
  return fmaxf(x, 0.0f) + __logf(1.0f + __expf(-fabsf(x)));
}

__device__ __forceinline__ void anchor_info(int a, const float* p8, const float* p16,
                                            const float* p32, int b, const float*& base,
                                            int& hw, int& HW, int& xg, int& yg, float& fs) {
  if (a < 6400)      { hw = a;        HW = 6400; xg = hw % 80; yg = hw / 80; fs = 8.f;
                       base = p8  + (size_t)b * 85 * 6400; }
  else if (a < 8000) { hw = a - 6400; HW = 1600; xg = hw % 40; yg = hw / 40; fs = 16.f;
                       base = p16 + (size_t)b * 85 * 1600; }
  else               { hw = a - 8000; HW = 400;  xg = hw % 20; yg = hw / 20; fs = 32.f;
                       base = p32 + (size_t)b * 85 * 400; }
}

__device__ __forceinline__ float iou_raw(float gx, float gy, float gw, float gh, float4 p) {
  float gtlx = gx - gw * 0.5f, gtly = gy - gh * 0.5f;
  float gbrx = gx + gw * 0.5f, gbry = gy + gh * 0.5f;
  float ptlx = p.x - p.z * 0.5f, ptly = p.y - p.w * 0.5f;
  float pbrx = p.x + p.z * 0.5f, pbry = p.y + p.w * 0.5f;
  float tlx = fmaxf(gtlx, ptlx), tly = fmaxf(gtly, ptly);
  float brx = fminf(gbrx, pbrx), bry = fminf(gbry, pbry);
  float inter = ((tlx < brx) && (tly < bry)) ? (brx - tlx) * (bry - tly) : 0.0f;
  float ag = gw * gh, ap = p.z * p.w;
  return inter * frcp(ag + ap - inter + 1e-16f);
}

// cost for anchor (lso, slr, am, base/hw/HW, bbox) vs gt g (box + class).
// Shared by scan and finalize so recomputation is bit-identical.
__device__ __forceinline__ float cost_for(float gx, float gy, float gw, float gh, int cg,
                                          int g, unsigned int am, float lso, float slr,
                                          const float* base, int hw, int HW, float4 pb,
                                          float& iou_out) {
  float x = base[(size_t)(5 + cg) * HW + hw];
  float u = __logf(1.0f + __expf(-fabsf(x)));
  float lsx = fminf(x, 0.0f) - u;
  float lpr = 0.5f * (lsx + lso);
  float p   = __expf(lpr);
  float l1p = fmaxf(__logf(1.0f - p), -100.0f);
  float wv  = fmaxf(lpr, -100.0f) - l1p;          // lp - l1p
  float iou = iou_raw(gx, gy, gw, gh, pb);
  iou_out = iou;
  float cst = -(wv + slr) - 3.0f * __logf(iou + 1e-8f);
  if (!((am >> g) & 1u)) cst += 100000.0f;
  return cst;
}

__device__ __forceinline__ float giou_loss(float4 bb, float gx, float gy, float gw, float gh) {
  float btlx = bb.x - bb.z * 0.5f, btly = bb.y - bb.w * 0.5f;
  float bbrx = bb.x + bb.z * 0.5f, bbry = bb.y + bb.w * 0.5f;
  float gtlx = gx - gw * 0.5f, gtly = gy - gh * 0.5f;
  float gbrx = gx + gw * 0.5f, gbry = gy + gh * 0.5f;
  float tlx = fmaxf(btlx, gtlx), tly = fmaxf(btly, gtly);
  float brx = fminf(bbrx, gbrx), bry = fminf(bbry, gbry);
  float area_b = bb.z * bb.w, area_g = gw * gh;
  float inter = ((tlx < brx) && (tly < bry)) ? (brx - tlx) * (bry - tly) : 0.0f;
  float uni = area_b + area_g - inter;
  float iou = inter / (uni + 1e-16f);
  float ctlx = fminf(btlx, gtlx), ctly = fminf(btly, gtly);
  float cbrx = fmaxf(bbrx, gbrx), cbry = fmaxf(bbry, gbry);
  float area_c = fmaxf((cbrx - ctlx) * (cbry - ctly), 1e-16f);
  float giou = iou - (area_c - uni) / area_c;
  giou = fminf(fmaxf(giou, -1.0f), 1.0f);
  return 1.0f - giou;
}

// ---------- kA: geometry + compaction + decode + obj-BCE + 80-class sums ----------
// No cost/iou table. Emits per fg anchor: meta {lso, slr, am, a}, bbox, sb.
__global__ __launch_bounds__(256) void kA(const float* __restrict__ p8,
                                          const float* __restrict__ p16,
                                          const float* __restrict__ p32,
                                          const float* __restrict__ labels,
                                          int* __restrict__ n_fg_cnt,
                                          float4* __restrict__ meta_c,
                                          float4* __restrict__ bbox_c,
                                          float* __restrict__ sb_c,
                                          unsigned int* __restrict__ match_c,
                                          float* __restrict__ blk_obj) {
  __shared__ float s_gt[NG * 4];
  __shared__ int   s_a[256];
  __shared__ unsigned int s_m[256];
  __shared__ float s_lso[256];
  __shared__ float s_sl[8][33];
  __shared__ float s_sbv[8][33];
  __shared__ unsigned int s_wcnt[4];
  __shared__ float s_part[4];
  __shared__ unsigned int s_base;
  __shared__ int s_cnt;

  int blk = blockIdx.x, b = blockIdx.y, tid = threadIdx.x, lane = tid & 63, wid = tid >> 6;
  size_t bo = (size_t)b * NAP;

  if (tid < NG) {
    s_gt[tid * 4 + 0] = labels[((size_t)b * NG + tid) * 5 + 0];
    s_gt[tid * 4 + 1] = labels[((size_t)b * NG + tid) * 5 + 1];
    s_gt[tid * 4 + 2] = labels[((size_t)b * NG + tid) * 5 + 2];
    s_gt[tid * 4 + 3] = labels[((size_t)b * NG + tid) * 5 + 3];
  }
  __syncthreads();

  // ---- phase 1: fg test + decode ----
  int a = blk * 256 + tid;
  match_c[bo + a] = 0u;                  // NBLK*256 == NAP: full coverage
  bool fg = false;
  unsigned int msk = 0u;
  float bce_obj = 0.0f, obj = 0.0f;
  const float* base = nullptr; int hw = 0, HW = 0, xg = 0, yg = 0; float fs = 8.f;
  if (a < NA) {
    anchor_info(a, p8, p16, p32, b, base, hw, HW, xg, yg, fs);
    obj = base[4 * HW + hw];             // coalesced obj-plane stream
    bce_obj = bce0(obj);
    float xc = ((float)xg + 0.5f) * fs;
    float yc = ((float)yg + 0.5f) * fs;
    float r = 2.5f * fs;
#pragma unroll
    for (int g = 0; g < NG; ++g) {
      float gx = s_gt[g * 4 + 0], gy = s_gt[g * 4 + 1];
      float gw = s_gt[g * 4 + 2], gh = s_gt[g * 4 + 3];
      bool inb = (xc > gx - 0.5f * gw) && (xc < gx + 0.5f * gw) &&
                 (yc > gy - 0.5f * gh) && (yc < gy + 0.5f * gh);
      bool inc = (xc > gx - r) && (xc < gx + r) && (yc > gy - r) && (yc < gy + r);
      fg = fg || inb || inc;
      if (inb && inc) msk |= (1u << g);
    }
  }

  unsigned long long bm = __ballot(fg);
#pragma unroll
  for (int off = 32; off; off >>= 1) bce_obj += __shfl_down(bce_obj, off, 64);
  if (lane == 0) { s_wcnt[wid] = (unsigned int)__popcll(bm); s_part[wid] = bce_obj; }
  __syncthreads();
  if (tid == 0) {
    unsigned int cnt = s_wcnt[0] + s_wcnt[1] + s_wcnt[2] + s_wcnt[3];
    s_cnt = (int)cnt;
    s_base = cnt ? (unsigned int)atomicAdd(&n_fg_cnt[b], (int)cnt) : 0u;
    blk_obj[b * NBLK + blk] = s_part[0] + s_part[1] + s_part[2] + s_part[3];
  }
  __syncthreads();

  if (fg) {
    unsigned int li = 0;
    for (int w = 0; w < wid; ++w) li += s_wcnt[w];
    li += (unsigned int)__popcll(bm & ((1ull << lane) - 1ull));
    float v0 = base[hw];
    float v1 = base[HW + hw];
    float v2 = base[2 * HW + hw];
    float v3 = base[3 * HW + hw];
    float4 bb4 = make_float4((v0 + (float)xg) * fs, (v1 + (float)yg) * fs,
                             __expf(v2) * fs, __expf(v3) * fs);
    float uo = __logf(1.0f + __expf(-fabsf(obj)));
    float lso = fminf(obj, 0.0f) - uo;   // log(sigmoid(obj))
    s_a[li] = a; s_m[li] = msk; s_lso[li] = lso;
    bbox_c[bo + s_base + li] = bb4;
  }
  __syncthreads();

  // ---- phase 2: 80-class sums (8 parts x 32 anchors) -> sb, slr; pack meta ----
  int cnt = s_cnt;
  int part = tid >> 5, cl = tid & 31;
  for (int t0 = 0; t0 < cnt; t0 += 32) {
    int idx = t0 + cl;
    bool act = idx < cnt;
    float sl = 0.0f, sb = 0.0f;
    if (act) {
      int a2 = s_a[idx];
      float lso = s_lso[idx];
      const float* base2; int hw2, HW2, xg2, yg2; float fs2;
      anchor_info(a2, p8, p16, p32, b, base2, hw2, HW2, xg2, yg2, fs2);
      const float* cb = base2 + (size_t)(5 + part * 10) * HW2 + hw2;
      float xs[10];
#pragma unroll
      for (int j = 0; j < 10; ++j) xs[j] = cb[(size_t)j * HW2];
#pragma unroll
      for (int j = 0; j < 10; ++j) {
        float x = xs[j];
        float u = __logf(1.0f + __expf(-fabsf(x)));
        sb += fmaxf(x, 0.0f) + u;                 // bce(x,0)
        float lsx = fminf(x, 0.0f) - u;           // log(sigmoid(x))
        float lpr = 0.5f * (lsx + lso);           // log p
        float p   = __expf(lpr);
        sl += fmaxf(__logf(1.0f - p), -100.0f);
      }
    }
    s_sl[part][cl] = sl;
    s_sbv[part][cl] = sb;
    __syncthreads();
    if (tid < 32) {
      int idx2 = t0 + tid;
      if (idx2 < cnt) {
        float tsl = 0.0f, tsb = 0.0f;
#pragma unroll
        for (int q = 0; q < 8; ++q) { tsl += s_sl[q][tid]; tsb += s_sbv[q][tid]; }
        int ci = (int)s_base + idx2;
        sb_c[bo + ci] = tsb;
        meta_c[bo + ci] = make_float4(s_lso[idx2], tsl,
                                      __uint_as_float(s_m[idx2]),
                                      __int_as_float(s_a[idx2]));
      }
    }
    __syncthreads();   // protect s_sl/s_sbv reuse next tile
  }
}

// ---------- kBG: per-(b,g) on-the-fly cost/iou + single-pass top-k + mark,
//             then per-image ticket finalize + final-scalar ticket ----------
__global__ __launch_bounds__(256) void kBG(const float* __restrict__ p8,
                                           const float* __restrict__ p16,
                                           const float* __restrict__ p32,
                                           const float* __restrict__ labels,
                                           const int* __restrict__ n_fg,
                                           const float4* __restrict__ meta_c,
                                           const float4* __restrict__ bbox_c,
                                           const float* __restrict__ sb_c,
                                           unsigned int* __restrict__ match_c,
                                           const float* __restrict__ blk_obj,
                                           float* __restrict__ accum,
                                           int* __restrict__ done_g,
                                           int* __restrict__ done_img,
                                           float* __restrict__ out) {
  __shared__ float s_gt[NG * 5];
  __shared__ float s_wt[4 * 10];
  __shared__ float s_wc[4 * 10];
  __shared__ int   s_wi[4 * 10];
  __shared__ float s_red[16];
  __shared__ int   s_flag;

  int g = blockIdx.x, b = blockIdx.y, tid = threadIdx.x;
  int lane = tid & 63, wid = tid >> 6;
  int n = n_fg[b];
  size_t bo = (size_t)b * NAP;

  if (tid < NG * 5) s_gt[tid] = labels[(size_t)b * NG * 5 + tid];
  __syncthreads();

  float ggx = s_gt[g * 5], ggy = s_gt[g * 5 + 1];
  float ggw = s_gt[g * 5 + 2], ggh = s_gt[g * 5 + 3];
  int   gcg = (int)s_gt[g * 5 + 4];

  float t10[10];          // top-10 ious (descending)
  float c10v[10];         // top-10 smallest costs (ascending)
  int   c10i[10];
#pragma unroll
  for (int j = 0; j < 10; ++j) { t10[j] = 0.0f; c10v[j] = 3.4e38f; c10i[j] = 0x7fffffff; }

  for (int ci = tid; ci < n; ci += 256) {
    float4 me = meta_c[bo + ci];
    float lso = me.x, slr = me.y;
    unsigned int am = __float_as_uint(me.z);
    int a = __float_as_int(me.w);
    const float* base; int hw, HW, xg, yg; float fs;
    anchor_info(a, p8, p16, p32, b, base, hw, HW, xg, yg, fs);
    float4 pb = bbox_c[bo + ci];
    float iou;
    float cst = cost_for(ggx, ggy, ggw, ggh, gcg, g, am, lso, slr, base, hw, HW, pb, iou);
    if (iou > t10[9]) {
      t10[9] = iou;
#pragma unroll
      for (int q = 9; q > 0; --q) {
        if (t10[q] > t10[q - 1]) { float t = t10[q]; t10[q] = t10[q - 1]; t10[q - 1] = t; }
        else break;
      }
    }
    if (cst < c10v[9] || (cst == c10v[9] && ci < c10i[9])) {
      c10v[9] = cst; c10i[9] = ci;
#pragma unroll
      for (int q = 9; q > 0; --q) {
        if (c10v[q] < c10v[q - 1] ||
            (c10v[q] == c10v[q - 1] && c10i[q] < c10i[q - 1])) {
          float tv = c10v[q]; c10v[q] = c10v[q - 1]; c10v[q - 1] = tv;
          int   ti = c10i[q]; c10i[q] = c10i[q - 1]; c10i[q - 1] = ti;
        } else break;
      }
    }
  }

  // per-wave extraction: 10 rounds; iou-max and cost-min chains interleaved (ILP)
  for (int r = 0; r < 10; ++r) {
    float v = t10[0];
    float bv = v;
    float cv = c10v[0]; int cix = c10i[0];
    float cbv = cv;     int cbi = cix;
#pragma unroll
    for (int off = 32; off; off >>= 1) {
      bv = fmaxf(bv, __shfl_down(bv, off, 64));
      float ov = __shfl_down(cbv, off, 64);
      int   oi = __shfl_down(cbi, off, 64);
      if (ov < cbv || (ov == cbv && oi < cbi)) { cbv = ov; cbi = oi; }
    }
    bv  = __shfl(bv, 0, 64);
    cbv = __shfl(cbv, 0, 64);
    cbi = __shfl(cbi, 0, 64);
    unsigned long long won = __ballot(v == bv);
    if (lane == __ffsll(won) - 1) {
#pragma unroll
      for (int q = 0; q < 9; ++q) t10[q] = t10[q + 1];
      t10[9] = -1.0f;
    }
    if (cv == cbv && cix == cbi) {       // unique owner (ci unique within block)
#pragma unroll
      for (int q = 0; q < 9; ++q) { c10v[q] = c10v[q + 1]; c10i[q] = c10i[q + 1]; }
      c10v[9] = 3.4e38f; c10i[9] = 0x7fffffff;
    }
    if (lane == 0) {
      s_wt[wid * 10 + r] = bv;
      s_wc[wid * 10 + r] = cbv;
      s_wi[wid * 10 + r] = cbi;
    }
  }
  __syncthreads();

  if (tid == 0) {
    // merge 4 sorted desc iou lists -> dyn_k (sum in desc order, trunc, clip 1)
    int p0 = 0, p1 = 0, p2 = 0, p3 = 0;
    float s = 0.0f;
    for (int r = 0; r < 10; ++r) {
      float v0 = (p0 < 10) ? s_wt[p0]      : -2.0f;
      float v1 = (p1 < 10) ? s_wt[10 + p1] : -2.0f;
      float v2 = (p2 < 10) ? s_wt[20 + p2] : -2.0f;
      float v3 = (p3 < 10) ? s_wt[30 + p3] : -2.0f;
      float m = fmaxf(fmaxf(v0, v1), fmaxf(v2, v3));
      s += m;
      if (m == v0) ++p0; else if (m == v1) ++p1; else if (m == v2) ++p2; else ++p3;
    }
    int k = (int)s;
    if (k < 1) k = 1;
    // merge 4 sorted asc (cost,ci) lists -> mark k smallest
    int q[4] = {0, 0, 0, 0};
    for (int it = 0; it < k; ++it) {
      float bv = 3.3e38f; int bi = 0x7fffffff; int sel = -1;
#pragma unroll
      for (int w = 0; w < 4; ++w) {
        if (q[w] < 10) {
          float v = s_wc[w * 10 + q[w]];
          int   i = s_wi[w * 10 + q[w]];
          if (v < bv || (v == bv && i < bi)) { bv = v; bi = i; sel = w; }
        }
      }
      if (sel < 0 || bv >= 1e37f) break;   // exhausted real candidates
      atomicOr(&match_c[bo + bi], 1u << g);
      ++q[sel];
    }
    // per-image ticket
    __threadfence();
    s_flag = (atomicAdd(&done_g[b], 1) == NG - 1) ? 1 : 0;
  }
  __syncthreads();
  if (!s_flag) return;

  // ---- finalize (winner block of image b) ----
  float li = 0.0f, oe = 0.0f, lc = 0.0f, nf = 0.0f;
  for (int ci = tid; ci < n; ci += 256) {
    unsigned int m = atomicOr(&match_c[bo + ci], 0u);   // coherence-point read
    if (m == 0u) continue;
    float4 me = meta_c[bo + ci];
    float lso = me.x, slr = me.y;
    unsigned int am = __float_as_uint(me.z);
    int a = __float_as_int(me.w);
    const float* base; int hw, HW, xg, yg; float fs;
    anchor_info(a, p8, p16, p32, b, base, hw, HW, xg, yg, fs);
    float4 pb = bbox_c[bo + ci];
    int mg;
    if (m & (m - 1)) {
      float bestc = 3.4e38f; mg = 0;
      for (int gq = 0; gq < NG; ++gq) {
        float iouq;
        float cq = cost_for(s_gt[gq * 5], s_gt[gq * 5 + 1], s_gt[gq * 5 + 2],
                            s_gt[gq * 5 + 3], (int)s_gt[gq * 5 + 4], gq, am,
                            lso, slr, base, hw, HW, pb, iouq);
        if (cq < bestc) { bestc = cq; mg = gq; }
      }
    } else {
      mg = __ffs(m) - 1;
    }
    float gx = s_gt[mg * 5], gy = s_gt[mg * 5 + 1];
    float gw = s_gt[mg * 5 + 2], gh = s_gt[mg * 5 + 3];
    int cgq = (int)s_gt[mg * 5 + 4];
    float piou = iou_raw(gx, gy, gw, gh, pb);
    li += giou_loss(pb, gx, gy, gw, gh);
    float xcls = base[(size_t)(5 + cgq) * HW + hw];
    lc += sb_c[bo + ci] - xcls * piou;   // bce(x,t) = bce(x,0) - x*t
    oe += base[4 * HW + hw];             // obj logit: bce(x,1) = bce(x,0) - x
    nf += 1.0f;
  }

  float vals[4] = {li, oe, lc, nf};
#pragma unroll
  for (int q2 = 0; q2 < 4; ++q2) {
#pragma unroll
    for (int off = 32; off; off >>= 1) vals[q2] += __shfl_down(vals[q2], off, 64);
  }
  if (lane == 0) {
    s_red[wid * 4 + 0] = vals[0];
    s_red[wid * 4 + 1] = vals[1];
    s_red[wid * 4 + 2] = vals[2];
    s_red[wid * 4 + 3] = vals[3];
  }
  __syncthreads();
  if (tid < 4) {
    const int slot[4] = {0, 2, 3, 4};
    float s = s_red[tid] + s_red[4 + tid] + s_red[8 + tid] + s_red[12 + tid];
    atomicAdd(&accum[slot[tid]], s);
  }

  // ---- final ticket: last image's finalize block emits the scalar ----
  if (tid == 0) {
    __threadfence();
    s_flag = (atomicAdd(done_img, 1) == NB - 1) ? 1 : 0;
  }
  __syncthreads();
  if (!s_flag) return;

  float s = 0.0f;
  for (int i = tid; i < NB * NBLK; i += 256) s += blk_obj[i];  // obj-BCE base
#pragma unroll
  for (int off = 32; off; off >>= 1) s += __shfl_down(s, off, 64);
  if ((tid & 63) == 0) s_red[tid >> 6] = s;
  __syncthreads();
  if (tid == 0) {
    float obj_base = s_red[0] + s_red[1] + s_red[2] + s_red[3];
    float loss_iou = atomicAdd(&accum[0], 0.0f);   // coherent read-backs
    float oex      = atomicAdd(&accum[2], 0.0f);
    float loss_cls = atomicAdd(&accum[3], 0.0f);
    float num_fg   = atomicAdd(&accum[4], 0.0f);
    float loss_obj = obj_base - oex;
    out[0] = (5.0f * loss_iou + loss_obj + loss_cls) / fmaxf(num_fg, 1.0f);
  }
}

// ---------- launch ----------
extern "C" void kernel_launch(void* const* d_in, const int* in_sizes, int n_in,
                              void* d_out, int out_size, void* d_ws, size_t ws_size,
                              hipStream_t stream) {
  const float* p8     = (const float*)d_in[0];
  const float* p16    = (const float*)d_in[1];
  const float* p32    = (const float*)d_in[2];
  const float* labels = (const float*)d_in[3];
  float* out = (float*)d_out;

  const size_t BAP = (size_t)NB * NAP;     // 270336
  char* w = (char*)d_ws;
  float4*       bbox_c   = (float4*)w;                             // 4.33 MB, 16B-aligned
  float4*       meta_c   = (float4*)(w + BAP * 16);                // 4.33 MB
  char*         w2       = w + BAP * 32;
  float*        sb_c     = (float*)(w2);
  unsigned int* match_c  = (unsigned int*)(w2 + BAP * 4);
  char*         w3       = w2 + BAP * 8;
  // zeroed region (512 B): n_fg(32i)@0, accum(8f)@128, done_g(32i)@256, done_img@384
  int*          n_fg     = (int*)w3;
  float*        accum    = (float*)(w3 + 128);
  int*          done_g   = (int*)(w3 + 256);
  int*          done_img = (int*)(w3 + 384);
  float*        blk_obj  = (float*)(w3 + 512);                     // NB*NBLK floats (4224 B)

  hipMemsetAsync(w3, 0, 512, stream);

  kA <<<dim3(NBLK, NB), dim3(256), 0, stream>>>(p8, p16, p32, labels, n_fg, meta_c,
                                                bbox_c, sb_c, match_c, blk_obj);
  kBG<<<dim3(NG, NB), dim3(256), 0, stream>>>(p8, p16, p32, labels, n_fg, meta_c, bbox_c,
                                              sb_c, match_c, blk_obj, accum, done_g,
                                              done_img, out);
}